// Round 12
// baseline (735.630 us; speedup 1.0000x reference)
//
#include <hip/hip_runtime.h>
#include <math.h>

#define NB   8192
#define TLEN 100
#define SEQ  101
#define DE   36
#define DM   72
#define NT   1024   // threads per block (16 waves)
#define NW   16     // waves per block
#define OPLD 104    // operand row stride (fp16 elems); mult of 8 -> 16B-aligned b128
#define OPN  10528  // 101*104 + 24-elem tail slack for A-phase k-tail reads (x0 weights)

// frag sets per resblock: A:4k*5n=20, B:3*7=21, C:3*5=15, D:3*5=15 -> 71
#define RB_SETS    71
#define TOTAL_SETS 142
#define LO_V4      (TOTAL_SETS * 64)   // uint4 offset of lo-frag array in ws

typedef _Float16 half8v __attribute__((ext_vector_type(8)));
typedef __attribute__((ext_vector_type(4))) float f32x4;
union U16 { uint4 u; half8v h; };

#define MFMAH(a, b, c) __builtin_amdgcn_mfma_f32_16x16x32_f16((a), (b), (c), 0, 0, 0)

static __device__ __forceinline__ unsigned short f2h(float f) {
  union { _Float16 h; unsigned short u; } c;
  c.h = (_Float16)f;
  return c.u;
}
static __device__ __forceinline__ float h2f(unsigned short u) {
  union { _Float16 h; unsigned short u; } c;
  c.u = u;
  return (float)c.h;
}

struct SetupParams {
  const float* tw1[2]; const float* tw2[2]; const float* cw1[2]; const float* cw2[2];
  unsigned* ws;
};

// Pack weights into MFMA B-fragment order as fp16 hi + fp16 lo (residual),
// zero-padded for k >= K and n >= N.  Slot bijection: k = kstep*32 + (lane>>4)*8 + e,
// n = ntile*16 + (lane&15); dword r holds elements e=2r (lo16) and e=2r+1 (hi16).
__global__ void setup_kernel(SetupParams sp) {
  int s = blockIdx.x;           // set id 0..141
  int tid = threadIdx.x;        // 256
  int l = tid >> 2, r = tid & 3;
  int rb = s / RB_SETS, s2 = s % RB_SETS;
  const float* W; int K, N, ks, nt;
  if (s2 < 20)      { ks = s2 / 5;        nt = s2 % 5;        W = sp.tw1[rb]; K = SEQ; N = DM; }
  else if (s2 < 41) { int t = s2 - 20; ks = t / 7; nt = t % 7; W = sp.tw2[rb]; K = DM;  N = SEQ; }
  else if (s2 < 56) { int t = s2 - 41; ks = t / 5; nt = t % 5; W = sp.cw1[rb]; K = DM;  N = DM; }
  else              { int t = s2 - 56; ks = t / 5; nt = t % 5; W = sp.cw2[rb]; K = DM;  N = DM; }
  int g = l >> 4;
  int n = nt * 16 + (l & 15);
  int k0 = ks * 32 + g * 8 + 2 * r;
  int k1 = k0 + 1;
  float f0 = (k0 < K && n < N) ? W[k0 * N + n] : 0.f;
  float f1 = (k1 < K && n < N) ? W[k1 * N + n] : 0.f;
  union { _Float16 h; unsigned short u; } h0, h1;
  h0.h = (_Float16)f0; h1.h = (_Float16)f1;
  unsigned short l0 = f2h(f0 - (float)h0.h), l1 = f2h(f1 - (float)h1.h);
  unsigned idx = (unsigned)s * 256u + (unsigned)l * 4u + (unsigned)r;
  sp.ws[idx] = (unsigned)h0.u | ((unsigned)h1.u << 16);
  sp.ws[(unsigned)TOTAL_SETS * 256u + idx] = (unsigned)l0 | ((unsigned)l1 << 16);
}

struct Params {
  const float *history; const int *ts; const int *target_ts; const int *task;
  const float *w_np; const float *b_np; const float *w_wp; const float *b_wp;
  const float *task_emb;
  const float *tb1[2]; const float *tb2[2]; const float *cb1[2]; const float *cb2[2];
  const float *wp_time; const float *bp_time; const float *w_head; const float *b_head;
  const uint4 *wf; float *out;
};

// GEMM phase across NW waves, per-tile fused epilogue: each tile's MFMA result
// is consumed immediately (src and dst LDS buffers are disjoint, epilogue cell
// ownership is per-wave disjoint -> no intra-phase barrier needed).  Live
// registers stay small (one tile's weights + one f32x4 acc) -> no spill.
template<int NTN, int NTILES, int KSTEPS, int MAXT, typename Epi>
static __device__ __forceinline__ void gemm_phase(
    const unsigned short* __restrict__ opb,
    const uint4* __restrict__ wf, int set_base, int lane, int wave, Epi epi) {
  const int g8 = (lane >> 4) * 8;
  const int m16 = lane & 15;
  #pragma unroll
  for (int i = 0; i < MAXT; ++i) {
    int tile = wave + i * NW;
    bool live = tile < NTILES;
    int tl = live ? tile : NTILES - 1;
    int mt = tl / NTN, nt = tl % NTN;
    int mrow = mt * 16 + m16; if (mrow > SEQ - 1) mrow = SEQ - 1;
    int abase = mrow * OPLD + g8;
    uint4 wh[KSTEPS], wl[KSTEPS];
    #pragma unroll
    for (int ks = 0; ks < KSTEPS; ++ks) {
      size_t off = (size_t)(set_base + ks * NTN + nt) * 64 + lane;
      wh[ks] = wf[off];
      wl[ks] = wf[(size_t)LO_V4 + off];
    }
    f32x4 a = {0.f, 0.f, 0.f, 0.f};
    #pragma unroll
    for (int ks = 0; ks < KSTEPS; ++ks) {
      half8v ah = *(const half8v*)&opb[abase + ks * 32];
      U16 h; h.u = wh[ks]; U16 l; l.u = wl[ks];
      a = MFMAH(ah, h.h, a);
      a = MFMAH(ah, l.h, a);
    }
    if (live) epi(mt, nt, a);
  }
}

__global__ __launch_bounds__(NT, 4) void fpfn_kernel(Params p) {
  __shared__ __align__(16) unsigned short R1[OPN];  // xT (fp16), [c][t]
  __shared__ __align__(16) unsigned short R2[OPN];  // x residual, [t][c] fp16
  __shared__ __align__(16) unsigned short R3[OPN];  // y1 [c][j] / y2 [t][j] fp16
  __shared__ float pe[640];
  __shared__ float sh[TLEN];                        // scaled history, later head partials
  __shared__ unsigned short datesu[TLEN * 4];

  const int tid  = threadIdx.x;
  const int b    = blockIdx.x;
  const int lane = tid & 63;
  const int wave = tid >> 6;

  // ---- zero operand buffers (pad regions must stay finite/zero) ----
  {
    uint4 z = {0, 0, 0, 0};
    uint4* z0 = (uint4*)R1;
    uint4* z1 = (uint4*)R2;
    uint4* z2 = (uint4*)R3;
    for (int i = tid; i < OPN / 8; i += NT) { z0[i] = z; z1[i] = z; z2[i] = z; }
  }

  float s = 0.f, hist_mean = 0.f;   // valid in wave 0 (used by tid 0 at the end)

  if (wave == 0) {
    // ---- robust_scale entirely in one wave (no block barriers) ----
    int t1 = lane + 64;
    bool v1 = (t1 < TLEN);
    float h0 = p.history[(size_t)b * TLEN + lane];
    float h1 = v1 ? p.history[(size_t)b * TLEN + t1] : 0.f;
    auto wred = [&](float v) -> float {
      #pragma unroll
      for (int o = 32; o > 0; o >>= 1) v += __shfl_xor(v, o, 64);
      return v;
    };
    float nz0 = (h0 != 0.f) ? 1.f : 0.f;
    float nz1 = (v1 && h1 != 0.f) ? 1.f : 0.f;
    float cnt  = wred(nz0 + nz1);
    float hsum = wred(h0 + h1);
    float safe = fmaxf(cnt, 1.f);
    float mean = hsum / safe;
    float var  = wred(nz0 * (h0 - mean) * (h0 - mean) + nz1 * (h1 - mean) * (h1 - mean)) / safe;
    float mean_z = (cnt > 0.f) ? mean : 0.f;
    float std_z  = (cnt > 0.f) ? sqrtf(var) : 0.f;
    float upper  = mean_z + 2.f * std_z;
    float c0v = fminf(fmaxf(h0, 0.f), upper);
    float c1v = fminf(fmaxf(h1, 0.f), upper);
    float m0 = (c0v != 0.f) ? 1.f : 0.f;
    float m1 = (v1 && c1v != 0.f) ? 1.f : 0.f;
    float cnt2 = wred(m0 + m1);
    float csum = wred(m0 * c0v + m1 * c1v);
    float safe2 = fmaxf(cnt2, 1.f);
    float mc = csum / safe2;
    float vc = wred(m0 * (c0v - mc) * (c0v - mc) + m1 * (c1v - mc) * (c1v - mc)) / safe2;
    float mc_z = (cnt2 > 0.f) ? mc : 0.f;
    float sc_z = (cnt2 > 0.f) ? sqrtf(vc) : 0.f;
    s = mc_z + sc_z + 1e-4f;
    hist_mean = hsum * (1.f / (float)TLEN);
    sh[lane] = fminf(fmaxf(h0 / s, 0.f), 3.f);
    if (v1) sh[t1] = fminf(fmaxf(h1 / s, 0.f), 3.f);
  } else {
    // ---- waves 1..15: positional tables + date offsets ----
    for (int idx = tid - 64; idx < 640; idx += (NT - 64)) {
      int periods, freqs, row, col;
      if (idx < 88)       { periods = 10; freqs = 4; row = idx >> 3;        col = idx & 7; }
      else if (idx < 192) { periods = 12; freqs = 4; row = (idx - 88) >> 3; col = (idx - 88) & 7; }
      else if (idx < 576) { periods = 31; freqs = 6; int r2 = idx - 192; row = r2 / 12; col = r2 - row * 12; }
      else                { periods = 7;  freqs = 4; row = (idx - 576) >> 3; col = (idx - 576) & 7; }
      int jf = (col < freqs) ? col : (col - freqs);
      float pip = (float)(3.14159265358979323846 / (double)periods);
      float ang = pip * (float)(1 << jf) * ((float)row - 1.0f);
      pe[idx] = (col < freqs) ? sinf(ang) : cosf(ang);
    }
    int t = tid - 64;
    if (t < TLEN) {
      int yr99 = p.ts[((size_t)b * TLEN + (TLEN - 1)) * 4 + 0];
      const int* tsb = p.ts + ((size_t)b * TLEN + t) * 4;
      int dy = yr99 - tsb[0]; dy = dy < 0 ? 0 : (dy > 10 ? 10 : dy);
      datesu[t * 4 + 0] = (unsigned short)(dy * 8);
      datesu[t * 4 + 1] = (unsigned short)(88  + tsb[1] * 8);
      datesu[t * 4 + 2] = (unsigned short)(192 + tsb[2] * 12);
      datesu[t * 4 + 3] = (unsigned short)(576 + tsb[3] * 8);
    }
  }
  __syncthreads();

  // ---- build x: fp16 into R2[t][j] and transposed into R1[j][t] ----
  for (int idx = tid; idx < DM * TLEN; idx += NT) {
    int j = idx / TLEN;
    int t = idx - j * TLEN;
    float sv = sh[t];
    float v;
    if (j < DE) {
      v = fmaxf(fmaf(sv, p.w_np[j], p.b_np[j]), 0.f);
    } else {
      int jj = j - DE;
      float e1 = fmaxf(fmaf(sv, p.w_wp[jj], p.b_wp[jj]), 0.f);
      float pv;
      if (jj < 8)       pv = pe[datesu[t * 4 + 0] + jj];
      else if (jj < 16) pv = pe[datesu[t * 4 + 1] + (jj - 8)];
      else if (jj < 28) pv = pe[datesu[t * 4 + 2] + (jj - 16)];
      else              pv = pe[datesu[t * 4 + 3] + (jj - 28)];
      v = e1 + pv;
    }
    unsigned short hv = f2h(v);
    R1[j * OPLD + t] = hv;
    R2[t * OPLD + j] = hv;
  }
  if (tid < DM) {  // target row t=100
    int tk = p.task[b];
    float te = p.task_emb[tk * DE + (tid < DE ? tid : tid - DE)];
    float v = te;
    if (tid >= DE) {
      int jj = tid - DE;
      const int* tt = p.target_ts + (size_t)b * 5;
      int yr99 = p.ts[((size_t)b * TLEN + (TLEN - 1)) * 4 + 0];
      int dy = yr99 - tt[0]; dy = dy < 0 ? 0 : (dy > 10 ? 10 : dy);
      float qv;
      if (jj < 8)       qv = pe[dy * 8 + jj];
      else if (jj < 16) qv = pe[88  + tt[1] * 8  + (jj - 8)];
      else if (jj < 28) qv = pe[192 + tt[2] * 12 + (jj - 16)];
      else              qv = pe[576 + tt[3] * 8  + (jj - 28)];
      v = te + qv;
    }
    unsigned short hv = f2h(v);
    R1[tid * OPLD + (SEQ - 1)] = hv;
    R2[(SEQ - 1) * OPLD + tid] = hv;
  }
  __syncthreads();

  const int m16 = lane & 15;
  const int rowb = (lane >> 4) * 4;

  #pragma unroll 1
  for (int rb = 0; rb < 2; ++rb) {
    const int base = rb * RB_SETS;
    const float* tb1 = p.tb1[rb]; const float* tb2 = p.tb2[rb];
    const float* cb1 = p.cb1[rb]; const float* cb2 = p.cb2[rb];

    // ---- A: y1[c][j] = relu(tb1[j] + sum_t xT[c][t] tw1[t][j]); src R1(xT) -> dst R3(y1) ----
    gemm_phase<5, 25, 4, 2>(R1, p.wf, base + 0, lane, wave,
      [&](int mt, int nt, f32x4 a) {
        int j = nt * 16 + m16;
        if (j < DM) {
          float bias = tb1[j];
          #pragma unroll
          for (int rg = 0; rg < 4; ++rg) {
            int c = mt * 16 + rowb + rg;
            if (c < DM) R3[c * OPLD + j] = f2h(fmaxf(a[rg] + bias, 0.f));
          }
        }
      });
    __syncthreads();

    // ---- B: x[t][c] += tb2[t] + sum_j y1[c][j] tw2[j][t]; src R3(y1), x update in R2 ----
    gemm_phase<7, 35, 3, 3>(R3, p.wf, base + 20, lane, wave,
      [&](int mt, int nt, f32x4 a) {
        int t = nt * 16 + m16;
        int c0 = mt * 16 + rowb;
        if (t < SEQ && c0 < DM) {        // c0 mult of 4; DM mult of 4 -> no straddle
          float bias = tb2[t];
          ushort4 xo = *(const ushort4*)&R2[t * OPLD + c0];
          ushort4 hx;
          hx.x = f2h(h2f(xo.x) + a[0] + bias);
          hx.y = f2h(h2f(xo.y) + a[1] + bias);
          hx.z = f2h(h2f(xo.z) + a[2] + bias);
          hx.w = f2h(h2f(xo.w) + a[3] + bias);
          *(ushort4*)&R2[t * OPLD + c0] = hx;
        }
      });
    __syncthreads();

    // ---- C: y2[t][j] = relu(cb1[j] + sum_c x[t][c] cw1[c][j]); src R2(x) -> dst R3(y2) ----
    gemm_phase<5, 35, 3, 3>(R2, p.wf, base + 41, lane, wave,
      [&](int mt, int nt, f32x4 a) {
        int j = nt * 16 + m16;
        if (j < DM) {
          float bias = cb1[j];
          #pragma unroll
          for (int rg = 0; rg < 4; ++rg) {
            int t = mt * 16 + rowb + rg;
            if (t < SEQ) R3[t * OPLD + j] = f2h(fmaxf(a[rg] + bias, 0.f));
          }
        }
      });
    __syncthreads();

    // ---- D: x[t][c] += cb2[c] + sum_j y2[t][j] cw2[j][c]; src R3(y2) -> R2 update + R1(xT) ----
    gemm_phase<5, 35, 3, 3>(R3, p.wf, base + 56, lane, wave,
      [&](int mt, int nt, f32x4 a) {
        int c = nt * 16 + m16;
        int t0 = mt * 16 + rowb;
        if (c < DM && t0 < SEQ) {
          float bias = cb2[c];
          ushort4 hx;
          float xn0 = h2f(R2[(t0 + 0) * OPLD + c]) + a[0] + bias;
          hx.x = f2h(xn0);
          R2[(t0 + 0) * OPLD + c] = hx.x;
          if (t0 + 3 < SEQ) {
            float xn1 = h2f(R2[(t0 + 1) * OPLD + c]) + a[1] + bias;
            float xn2 = h2f(R2[(t0 + 2) * OPLD + c]) + a[2] + bias;
            float xn3 = h2f(R2[(t0 + 3) * OPLD + c]) + a[3] + bias;
            hx.y = f2h(xn1); hx.z = f2h(xn2); hx.w = f2h(xn3);
            R2[(t0 + 1) * OPLD + c] = hx.y;
            R2[(t0 + 2) * OPLD + c] = hx.z;
            R2[(t0 + 3) * OPLD + c] = hx.w;
            *(ushort4*)&R1[c * OPLD + t0] = hx;   // xT for next resblock's A
          } else {
            R1[c * OPLD + t0] = hx.x;
            #pragma unroll
            for (int rg = 1; rg < 4; ++rg) {
              int t = t0 + rg;
              if (t < SEQ) {
                float xn = h2f(R2[t * OPLD + c]) + a[rg] + bias;
                unsigned short hv = f2h(xn);
                R2[t * OPLD + c] = hv;
                R1[c * OPLD + t] = hv;
              }
            }
          }
        }
      });
    __syncthreads();
  }

  // ---- head (fp32 math on fp16 x) ----
  if (tid < DM) {
    float a = 0.f;
    for (int t = 0; t < SEQ; ++t) a = fmaf(h2f(R2[t * OPLD + tid]), p.wp_time[t], a);
    sh[tid] = (a + p.bp_time[0]) * p.w_head[tid];
  }
  __syncthreads();
  if (tid == 0) {
    float yv = 0.f;
    #pragma unroll 8
    for (int i = 0; i < DM; ++i) yv += sh[i];
    yv = fmaxf(yv + p.b_head[0], 0.f);
    p.out[b]      = yv * s + hist_mean;
    p.out[NB + b] = s;
  }
}

extern "C" void kernel_launch(void* const* d_in, const int* in_sizes, int n_in,
                              void* d_out, int out_size, void* d_ws, size_t ws_size,
                              hipStream_t stream) {
  (void)in_sizes; (void)n_in; (void)out_size; (void)ws_size;

  SetupParams sp;
  sp.tw1[0] = (const float*)d_in[9];  sp.tw2[0] = (const float*)d_in[11];
  sp.cw1[0] = (const float*)d_in[13]; sp.cw2[0] = (const float*)d_in[15];
  sp.tw1[1] = (const float*)d_in[17]; sp.tw2[1] = (const float*)d_in[19];
  sp.cw1[1] = (const float*)d_in[21]; sp.cw2[1] = (const float*)d_in[23];
  sp.ws = (unsigned*)d_ws;
  hipLaunchKernelGGL(setup_kernel, dim3(TOTAL_SETS), dim3(256), 0, stream, sp);

  Params p;
  p.history   = (const float*)d_in[0];
  p.ts        = (const int*)  d_in[1];
  p.target_ts = (const int*)  d_in[2];
  p.task      = (const int*)  d_in[3];
  p.w_np = (const float*)d_in[4];  p.b_np = (const float*)d_in[5];
  p.w_wp = (const float*)d_in[6];  p.b_wp = (const float*)d_in[7];
  p.task_emb = (const float*)d_in[8];
  p.tb1[0] = (const float*)d_in[10]; p.tb2[0] = (const float*)d_in[12];
  p.cb1[0] = (const float*)d_in[14]; p.cb2[0] = (const float*)d_in[16];
  p.tb1[1] = (const float*)d_in[18]; p.tb2[1] = (const float*)d_in[20];
  p.cb1[1] = (const float*)d_in[22]; p.cb2[1] = (const float*)d_in[24];
  p.wp_time = (const float*)d_in[25]; p.bp_time = (const float*)d_in[26];
  p.w_head  = (const float*)d_in[27]; p.b_head  = (const float*)d_in[28];
  p.wf  = (const uint4*)d_ws;
  p.out = (float*)d_out;
  hipLaunchKernelGGL(fpfn_kernel, dim3(NB), dim3(NT), 0, stream, p);
}

// Round 13
// 576.275 us; speedup vs baseline: 1.2765x; 1.2765x over previous
//
#include <hip/hip_runtime.h>
#include <math.h>

#define NB   8192
#define TLEN 100
#define SEQ  101
#define DE   36
#define DM   72
#define NT   512    // threads per block (8 waves)
#define NW   8      // waves per block
#define OPLD 104    // operand row stride (fp16 elems); mult of 8 -> 16B-aligned b128
#define OPN  10528  // 101*104 + 24-elem tail slack for A-phase k-tail reads (x0 weights)

// frag sets per resblock: A:4k*5n=20, B:3*7=21, C:3*5=15, D:3*5=15 -> 71
#define RB_SETS    71
#define TOTAL_SETS 142
#define LO_V4      (TOTAL_SETS * 64)   // uint4 offset of lo-frag array in ws

typedef _Float16 half8v __attribute__((ext_vector_type(8)));
typedef __attribute__((ext_vector_type(4))) float f32x4;
union U16 { uint4 u; half8v h; };

#define MFMAH(a, b, c) __builtin_amdgcn_mfma_f32_16x16x32_f16((a), (b), (c), 0, 0, 0)

static __device__ __forceinline__ unsigned short f2h(float f) {
  union { _Float16 h; unsigned short u; } c;
  c.h = (_Float16)f;
  return c.u;
}
static __device__ __forceinline__ float h2f(unsigned short u) {
  union { _Float16 h; unsigned short u; } c;
  c.u = u;
  return (float)c.h;
}

struct SetupParams {
  const float* tw1[2]; const float* tw2[2]; const float* cw1[2]; const float* cw2[2];
  unsigned* ws;
};

// Pack weights into MFMA fragment order as fp16 hi + fp16 lo (residual),
// zero-padded for k >= K and n >= N.  Slot bijection: k = kstep*32 + (lane>>4)*8 + e,
// n = ntile*16 + (lane&15); dword r holds elements e=2r (lo16) and e=2r+1 (hi16).
// A- and B-operand fragments share this bijection, so the same packed data
// serves either operand slot (used for the operand-swap trick below).
__global__ void setup_kernel(SetupParams sp) {
  int s = blockIdx.x;           // set id 0..141
  int tid = threadIdx.x;        // 256
  int l = tid >> 2, r = tid & 3;
  int rb = s / RB_SETS, s2 = s % RB_SETS;
  const float* W; int K, N, ks, nt;
  if (s2 < 20)      { ks = s2 / 5;        nt = s2 % 5;        W = sp.tw1[rb]; K = SEQ; N = DM; }
  else if (s2 < 41) { int t = s2 - 20; ks = t / 7; nt = t % 7; W = sp.tw2[rb]; K = DM;  N = SEQ; }
  else if (s2 < 56) { int t = s2 - 41; ks = t / 5; nt = t % 5; W = sp.cw1[rb]; K = DM;  N = DM; }
  else              { int t = s2 - 56; ks = t / 5; nt = t % 5; W = sp.cw2[rb]; K = DM;  N = DM; }
  int g = l >> 4;
  int n = nt * 16 + (l & 15);
  int k0 = ks * 32 + g * 8 + 2 * r;
  int k1 = k0 + 1;
  float f0 = (k0 < K && n < N) ? W[k0 * N + n] : 0.f;
  float f1 = (k1 < K && n < N) ? W[k1 * N + n] : 0.f;
  union { _Float16 h; unsigned short u; } h0, h1;
  h0.h = (_Float16)f0; h1.h = (_Float16)f1;
  unsigned short l0 = f2h(f0 - (float)h0.h), l1 = f2h(f1 - (float)h1.h);
  unsigned idx = (unsigned)s * 256u + (unsigned)l * 4u + (unsigned)r;
  sp.ws[idx] = (unsigned)h0.u | ((unsigned)h1.u << 16);
  sp.ws[(unsigned)TOTAL_SETS * 256u + idx] = (unsigned)l0 | ((unsigned)l1 << 16);
}

struct Params {
  const float *history; const int *ts; const int *target_ts; const int *task;
  const float *w_np; const float *b_np; const float *w_wp; const float *b_wp;
  const float *task_emb;
  const float *tb1[2]; const float *tb2[2]; const float *cb1[2]; const float *cb2[2];
  const float *wp_time; const float *bp_time; const float *w_head; const float *b_head;
  const uint4 *wf; float *out;
};

// GEMM phase across NW waves, per-tile fused epilogue.
// SWAP=false: D = mfma(x_frag, W_frag)  -> col(lane&15)=weight-dim, rows(regs)=x-dim.
// SWAP=true : D = mfma(W_frag, x_frag)  -> col(lane&15)=x-dim,      rows(regs)=weight-dim
//             (same values; lets the epilogue write 4 consecutive weight-dim
//              elements as one ushort4 into a row-major [x][w] buffer).
template<int NTN, int NTILES, int KSTEPS, int MAXT, bool SWAP, typename Epi>
static __device__ __forceinline__ void gemm_phase(
    const unsigned short* __restrict__ opb,
    const uint4* __restrict__ wf, int set_base, int lane, int wave, Epi epi) {
  const int g8 = (lane >> 4) * 8;
  const int m16 = lane & 15;
  #pragma unroll
  for (int i = 0; i < MAXT; ++i) {
    int tile = wave + i * NW;
    bool live = tile < NTILES;
    int tl = live ? tile : NTILES - 1;
    int mt = tl / NTN, nt = tl % NTN;    // mt: x-row tile, nt: weight tile
    int mrow = mt * 16 + m16; if (mrow > SEQ - 1) mrow = SEQ - 1;
    int abase = mrow * OPLD + g8;
    uint4 wh[KSTEPS], wl[KSTEPS];
    #pragma unroll
    for (int ks = 0; ks < KSTEPS; ++ks) {
      size_t off = (size_t)(set_base + ks * NTN + nt) * 64 + lane;
      wh[ks] = wf[off];
      wl[ks] = wf[(size_t)LO_V4 + off];
    }
    f32x4 a = {0.f, 0.f, 0.f, 0.f};
    #pragma unroll
    for (int ks = 0; ks < KSTEPS; ++ks) {
      half8v ah = *(const half8v*)&opb[abase + ks * 32];
      U16 h; h.u = wh[ks]; U16 l; l.u = wl[ks];
      if (SWAP) {
        a = MFMAH(h.h, ah, a);
        a = MFMAH(l.h, ah, a);
      } else {
        a = MFMAH(ah, h.h, a);
        a = MFMAH(ah, l.h, a);
      }
    }
    if (live) epi(mt, nt, a);
  }
}

__global__ __launch_bounds__(NT, 4) void fpfn_kernel(Params p) {
  __shared__ __align__(16) unsigned short R1[OPN];  // xT (fp16), [c][t]
  __shared__ __align__(16) unsigned short R2[OPN];  // x residual, [t][c] fp16
  __shared__ __align__(16) unsigned short R3[OPN];  // y1 [c][j] / y2 [t][j] fp16
  __shared__ float pe[640];
  __shared__ float sh[TLEN];                        // scaled history, later head partials
  __shared__ unsigned short datesu[TLEN * 4];

  const int tid  = threadIdx.x;
  const int b    = blockIdx.x;
  const int lane = tid & 63;
  const int wave = tid >> 6;

  // ---- zero operand buffers (pad regions must stay finite/zero) ----
  {
    uint4 z = {0, 0, 0, 0};
    uint4* z0 = (uint4*)R1;
    uint4* z1 = (uint4*)R2;
    uint4* z2 = (uint4*)R3;
    for (int i = tid; i < OPN / 8; i += NT) { z0[i] = z; z1[i] = z; z2[i] = z; }
  }

  float s = 0.f, hist_mean = 0.f;   // valid in wave 0 (used by tid 0 at the end)

  if (wave == 0) {
    // ---- robust_scale entirely in one wave (no block barriers) ----
    int t1 = lane + 64;
    bool v1 = (t1 < TLEN);
    float h0 = p.history[(size_t)b * TLEN + lane];
    float h1 = v1 ? p.history[(size_t)b * TLEN + t1] : 0.f;
    auto wred = [&](float v) -> float {
      #pragma unroll
      for (int o = 32; o > 0; o >>= 1) v += __shfl_xor(v, o, 64);
      return v;
    };
    float nz0 = (h0 != 0.f) ? 1.f : 0.f;
    float nz1 = (v1 && h1 != 0.f) ? 1.f : 0.f;
    float cnt  = wred(nz0 + nz1);
    float hsum = wred(h0 + h1);
    float safe = fmaxf(cnt, 1.f);
    float mean = hsum / safe;
    float var  = wred(nz0 * (h0 - mean) * (h0 - mean) + nz1 * (h1 - mean) * (h1 - mean)) / safe;
    float mean_z = (cnt > 0.f) ? mean : 0.f;
    float std_z  = (cnt > 0.f) ? sqrtf(var) : 0.f;
    float upper  = mean_z + 2.f * std_z;
    float c0v = fminf(fmaxf(h0, 0.f), upper);
    float c1v = fminf(fmaxf(h1, 0.f), upper);
    float m0 = (c0v != 0.f) ? 1.f : 0.f;
    float m1 = (v1 && c1v != 0.f) ? 1.f : 0.f;
    float cnt2 = wred(m0 + m1);
    float csum = wred(m0 * c0v + m1 * c1v);
    float safe2 = fmaxf(cnt2, 1.f);
    float mc = csum / safe2;
    float vc = wred(m0 * (c0v - mc) * (c0v - mc) + m1 * (c1v - mc) * (c1v - mc)) / safe2;
    float mc_z = (cnt2 > 0.f) ? mc : 0.f;
    float sc_z = (cnt2 > 0.f) ? sqrtf(vc) : 0.f;
    s = mc_z + sc_z + 1e-4f;
    hist_mean = hsum * (1.f / (float)TLEN);
    sh[lane] = fminf(fmaxf(h0 / s, 0.f), 3.f);
    if (v1) sh[t1] = fminf(fmaxf(h1 / s, 0.f), 3.f);
  } else {
    // ---- waves 1-7: positional tables + date offsets ----
    for (int idx = tid - 64; idx < 640; idx += (NT - 64)) {
      int periods, freqs, row, col;
      if (idx < 88)       { periods = 10; freqs = 4; row = idx >> 3;        col = idx & 7; }
      else if (idx < 192) { periods = 12; freqs = 4; row = (idx - 88) >> 3; col = (idx - 88) & 7; }
      else if (idx < 576) { periods = 31; freqs = 6; int r2 = idx - 192; row = r2 / 12; col = r2 - row * 12; }
      else                { periods = 7;  freqs = 4; row = (idx - 576) >> 3; col = (idx - 576) & 7; }
      int jf = (col < freqs) ? col : (col - freqs);
      float pip = (float)(3.14159265358979323846 / (double)periods);
      float ang = pip * (float)(1 << jf) * ((float)row - 1.0f);
      pe[idx] = (col < freqs) ? sinf(ang) : cosf(ang);
    }
    int t = tid - 64;
    if (t < TLEN) {
      int yr99 = p.ts[((size_t)b * TLEN + (TLEN - 1)) * 4 + 0];
      const int* tsb = p.ts + ((size_t)b * TLEN + t) * 4;
      int dy = yr99 - tsb[0]; dy = dy < 0 ? 0 : (dy > 10 ? 10 : dy);
      datesu[t * 4 + 0] = (unsigned short)(dy * 8);
      datesu[t * 4 + 1] = (unsigned short)(88  + tsb[1] * 8);
      datesu[t * 4 + 2] = (unsigned short)(192 + tsb[2] * 12);
      datesu[t * 4 + 3] = (unsigned short)(576 + tsb[3] * 8);
    }
  }
  __syncthreads();

  // ---- build x: fp16 into R2[t][j] and transposed into R1[j][t] ----
  for (int idx = tid; idx < DM * TLEN; idx += NT) {
    int j = idx / TLEN;
    int t = idx - j * TLEN;
    float sv = sh[t];
    float v;
    if (j < DE) {
      v = fmaxf(fmaf(sv, p.w_np[j], p.b_np[j]), 0.f);
    } else {
      int jj = j - DE;
      float e1 = fmaxf(fmaf(sv, p.w_wp[jj], p.b_wp[jj]), 0.f);
      float pv;
      if (jj < 8)       pv = pe[datesu[t * 4 + 0] + jj];
      else if (jj < 16) pv = pe[datesu[t * 4 + 1] + (jj - 8)];
      else if (jj < 28) pv = pe[datesu[t * 4 + 2] + (jj - 16)];
      else              pv = pe[datesu[t * 4 + 3] + (jj - 28)];
      v = e1 + pv;
    }
    unsigned short hv = f2h(v);
    R1[j * OPLD + t] = hv;
    R2[t * OPLD + j] = hv;
  }
  if (tid < DM) {  // target row t=100
    int tk = p.task[b];
    float te = p.task_emb[tk * DE + (tid < DE ? tid : tid - DE)];
    float v = te;
    if (tid >= DE) {
      int jj = tid - DE;
      const int* tt = p.target_ts + (size_t)b * 5;
      int yr99 = p.ts[((size_t)b * TLEN + (TLEN - 1)) * 4 + 0];
      int dy = yr99 - tt[0]; dy = dy < 0 ? 0 : (dy > 10 ? 10 : dy);
      float qv;
      if (jj < 8)       qv = pe[dy * 8 + jj];
      else if (jj < 16) qv = pe[88  + tt[1] * 8  + (jj - 8)];
      else if (jj < 28) qv = pe[192 + tt[2] * 12 + (jj - 16)];
      else              qv = pe[576 + tt[3] * 8  + (jj - 28)];
      v = te + qv;
    }
    unsigned short hv = f2h(v);
    R1[tid * OPLD + (SEQ - 1)] = hv;
    R2[(SEQ - 1) * OPLD + tid] = hv;
  }
  __syncthreads();

  const int m16 = lane & 15;
  const int rowb = (lane >> 4) * 4;

  #pragma unroll 1
  for (int rb = 0; rb < 2; ++rb) {
    const int base = rb * RB_SETS;
    const float* tb1 = p.tb1[rb]; const float* tb2 = p.tb2[rb];
    const float* cb1 = p.cb1[rb]; const float* cb2 = p.cb2[rb];

    // ---- A (SWAP): y1[c][j] = relu(tb1[j] + sum_t xT[c][t] tw1[t][j]);
    //      src R1(xT) -> dst R3(y1 as [c][j]); lane col=c, regs=j -> ushort4 write ----
    gemm_phase<5, 25, 4, 4, true>(R1, p.wf, base + 0, lane, wave,
      [&](int mt, int nt, f32x4 a) {
        int c  = mt * 16 + m16;
        int j0 = nt * 16 + rowb;
        if (c < DM && j0 < DM) {
          float4 b4 = *(const float4*)&tb1[j0];
          ushort4 hx;
          hx.x = f2h(fmaxf(a[0] + b4.x, 0.f));
          hx.y = f2h(fmaxf(a[1] + b4.y, 0.f));
          hx.z = f2h(fmaxf(a[2] + b4.z, 0.f));
          hx.w = f2h(fmaxf(a[3] + b4.w, 0.f));
          *(ushort4*)&R3[c * OPLD + j0] = hx;
        }
      });
    __syncthreads();

    // ---- B (no swap): x[t][c] += tb2[t] + sum_j y1[c][j] tw2[j][t];
    //      src R3(y1), x update in R2; lane col=t, regs=c -> ushort4 R2 rmw ----
    gemm_phase<7, 35, 3, 5, false>(R3, p.wf, base + 20, lane, wave,
      [&](int mt, int nt, f32x4 a) {
        int t  = nt * 16 + m16;
        int c0 = mt * 16 + rowb;
        if (t < SEQ && c0 < DM) {        // c0 mult of 4; DM mult of 4 -> no straddle
          float bias = tb2[t];
          ushort4 xo = *(const ushort4*)&R2[t * OPLD + c0];
          ushort4 hx;
          hx.x = f2h(h2f(xo.x) + a[0] + bias);
          hx.y = f2h(h2f(xo.y) + a[1] + bias);
          hx.z = f2h(h2f(xo.z) + a[2] + bias);
          hx.w = f2h(h2f(xo.w) + a[3] + bias);
          *(ushort4*)&R2[t * OPLD + c0] = hx;
        }
      });
    __syncthreads();

    // ---- C (SWAP): y2[t][j] = relu(cb1[j] + sum_c x[t][c] cw1[c][j]);
    //      src R2(x) -> dst R3(y2 as [t][j]); lane col=t, regs=j -> ushort4 write ----
    gemm_phase<5, 35, 3, 5, true>(R2, p.wf, base + 41, lane, wave,
      [&](int mt, int nt, f32x4 a) {
        int t  = mt * 16 + m16;
        int j0 = nt * 16 + rowb;
        if (t < SEQ && j0 < DM) {
          float4 b4 = *(const float4*)&cb1[j0];
          ushort4 hx;
          hx.x = f2h(fmaxf(a[0] + b4.x, 0.f));
          hx.y = f2h(fmaxf(a[1] + b4.y, 0.f));
          hx.z = f2h(fmaxf(a[2] + b4.z, 0.f));
          hx.w = f2h(fmaxf(a[3] + b4.w, 0.f));
          *(ushort4*)&R3[t * OPLD + j0] = hx;
        }
      });
    __syncthreads();

    // ---- D (SWAP): x[t][c] += cb2[c] + sum_j y2[t][j] cw2[j][c];
    //      src R3(y2) -> R2 rmw (ushort4) + R1 xT (4 scalar) ----
    gemm_phase<5, 35, 3, 5, true>(R3, p.wf, base + 56, lane, wave,
      [&](int mt, int nt, f32x4 a) {
        int t  = mt * 16 + m16;
        int c0 = nt * 16 + rowb;
        if (t < SEQ && c0 < DM) {
          float4 cb4 = *(const float4*)&cb2[c0];
          ushort4 xo = *(const ushort4*)&R2[t * OPLD + c0];
          ushort4 hx;
          hx.x = f2h(h2f(xo.x) + a[0] + cb4.x);
          hx.y = f2h(h2f(xo.y) + a[1] + cb4.y);
          hx.z = f2h(h2f(xo.z) + a[2] + cb4.z);
          hx.w = f2h(h2f(xo.w) + a[3] + cb4.w);
          *(ushort4*)&R2[t * OPLD + c0] = hx;
          R1[(c0 + 0) * OPLD + t] = hx.x;   // xT for next resblock's A
          R1[(c0 + 1) * OPLD + t] = hx.y;
          R1[(c0 + 2) * OPLD + t] = hx.z;
          R1[(c0 + 3) * OPLD + t] = hx.w;
        }
      });
    __syncthreads();
  }

  // ---- head (fp32 math on fp16 x) ----
  if (tid < DM) {
    float a = 0.f;
    for (int t = 0; t < SEQ; ++t) a = fmaf(h2f(R2[t * OPLD + tid]), p.wp_time[t], a);
    sh[tid] = (a + p.bp_time[0]) * p.w_head[tid];
  }
  __syncthreads();
  if (tid == 0) {
    float yv = 0.f;
    #pragma unroll 8
    for (int i = 0; i < DM; ++i) yv += sh[i];
    yv = fmaxf(yv + p.b_head[0], 0.f);
    p.out[b]      = yv * s + hist_mean;
    p.out[NB + b] = s;
  }
}

extern "C" void kernel_launch(void* const* d_in, const int* in_sizes, int n_in,
                              void* d_out, int out_size, void* d_ws, size_t ws_size,
                              hipStream_t stream) {
  (void)in_sizes; (void)n_in; (void)out_size; (void)ws_size;

  SetupParams sp;
  sp.tw1[0] = (const float*)d_in[9];  sp.tw2[0] = (const float*)d_in[11];
  sp.cw1[0] = (const float*)d_in[13]; sp.cw2[0] = (const float*)d_in[15];
  sp.tw1[1] = (const float*)d_in[17]; sp.tw2[1] = (const float*)d_in[19];
  sp.cw1[1] = (const float*)d_in[21]; sp.cw2[1] = (const float*)d_in[23];
  sp.ws = (unsigned*)d_ws;
  hipLaunchKernelGGL(setup_kernel, dim3(TOTAL_SETS), dim3(256), 0, stream, sp);

  Params p;
  p.history   = (const float*)d_in[0];
  p.ts        = (const int*)  d_in[1];
  p.target_ts = (const int*)  d_in[2];
  p.task      = (const int*)  d_in[3];
  p.w_np = (const float*)d_in[4];  p.b_np = (const float*)d_in[5];
  p.w_wp = (const float*)d_in[6];  p.b_wp = (const float*)d_in[7];
  p.task_emb = (const float*)d_in[8];
  p.tb1[0] = (const float*)d_in[10]; p.tb2[0] = (const float*)d_in[12];
  p.cb1[0] = (const float*)d_in[14]; p.cb2[0] = (const float*)d_in[16];
  p.tb1[1] = (const float*)d_in[18]; p.tb2[1] = (const float*)d_in[20];
  p.cb1[1] = (const float*)d_in[22]; p.cb2[1] = (const float*)d_in[24];
  p.wp_time = (const float*)d_in[25]; p.bp_time = (const float*)d_in[26];
  p.w_head  = (const float*)d_in[27]; p.b_head  = (const float*)d_in[28];
  p.wf  = (const uint4*)d_ws;
  p.out = (float*)d_out;
  hipLaunchKernelGGL(fpfn_kernel, dim3(NB), dim3(NT), 0, stream, p);
}

// Round 14
// 398.292 us; speedup vs baseline: 1.8470x; 1.4469x over previous
//
#include <hip/hip_runtime.h>
#include <math.h>

#define NB   8192
#define TLEN 100
#define SEQ  101
#define DE   36
#define DM   72
#define NT   512    // threads per block (8 waves)
#define NW   8      // waves per block
#define OPLD 104    // operand row stride (fp16 elems); mult of 8 -> 16B-aligned b128
#define OPN  10528  // 101*104 + tail slack for clamped k-tail reads (x0 weights)

// frag sets per resblock: A:4k*5n=20, B:3*7=21, C:3*5=15, D:3*5=15 -> 71
#define RB_SETS    71
#define TOTAL_SETS 142
#define LO_V4      (TOTAL_SETS * 64)   // uint4 offset of lo-frag array in ws

typedef _Float16 half8v __attribute__((ext_vector_type(8)));
typedef __attribute__((ext_vector_type(4))) float f32x4;
union U16 { uint4 u; half8v h; };

#define MFMAH(a, b, c) __builtin_amdgcn_mfma_f32_16x16x32_f16((a), (b), (c), 0, 0, 0)

static __device__ __forceinline__ unsigned short f2h(float f) {
  union { _Float16 h; unsigned short u; } c;
  c.h = (_Float16)f;
  return c.u;
}
static __device__ __forceinline__ float h2f(unsigned short u) {
  union { _Float16 h; unsigned short u; } c;
  c.u = u;
  return (float)c.h;
}

struct SetupParams {
  const float* tw1[2]; const float* tw2[2]; const float* cw1[2]; const float* cw2[2];
  unsigned* ws;
};

// Pack weights into MFMA fragment order as fp16 hi + fp16 lo (residual),
// zero-padded for k >= K and n >= N.  Slot bijection: k = kstep*32 + (lane>>4)*8 + e,
// n = ntile*16 + (lane&15); dword r holds elements e=2r (lo16) and e=2r+1 (hi16).
// A- and B-operand fragments share this bijection (operand-swap safe).
__global__ void setup_kernel(SetupParams sp) {
  int s = blockIdx.x;           // set id 0..141
  int tid = threadIdx.x;        // 256
  int l = tid >> 2, r = tid & 3;
  int rb = s / RB_SETS, s2 = s % RB_SETS;
  const float* W; int K, N, ks, nt;
  if (s2 < 20)      { ks = s2 / 5;        nt = s2 % 5;        W = sp.tw1[rb]; K = SEQ; N = DM; }
  else if (s2 < 41) { int t = s2 - 20; ks = t / 7; nt = t % 7; W = sp.tw2[rb]; K = DM;  N = SEQ; }
  else if (s2 < 56) { int t = s2 - 41; ks = t / 5; nt = t % 5; W = sp.cw1[rb]; K = DM;  N = DM; }
  else              { int t = s2 - 56; ks = t / 5; nt = t % 5; W = sp.cw2[rb]; K = DM;  N = DM; }
  int g = l >> 4;
  int n = nt * 16 + (l & 15);
  int k0 = ks * 32 + g * 8 + 2 * r;
  int k1 = k0 + 1;
  float f0 = (k0 < K && n < N) ? W[k0 * N + n] : 0.f;
  float f1 = (k1 < K && n < N) ? W[k1 * N + n] : 0.f;
  union { _Float16 h; unsigned short u; } h0, h1;
  h0.h = (_Float16)f0; h1.h = (_Float16)f1;
  unsigned short l0 = f2h(f0 - (float)h0.h), l1 = f2h(f1 - (float)h1.h);
  unsigned idx = (unsigned)s * 256u + (unsigned)l * 4u + (unsigned)r;
  sp.ws[idx] = (unsigned)h0.u | ((unsigned)h1.u << 16);
  sp.ws[(unsigned)TOTAL_SETS * 256u + idx] = (unsigned)l0 | ((unsigned)l1 << 16);
}

struct Params {
  const float *history; const int *ts; const int *target_ts; const int *task;
  const float *w_np; const float *b_np; const float *w_wp; const float *b_wp;
  const float *task_emb;
  const float *tb1[2]; const float *tb2[2]; const float *cb1[2]; const float *cb2[2];
  const float *wp_time; const float *bp_time; const float *w_head; const float *b_head;
  const uint4 *wf; float *out;
};

// Column-ownership GEMM phase: each wave owns ONE weight column (nt) and
// iterates the row tiles of that column, so the column's weight fragments are
// loaded from L2 exactly once per wave and reused 3-7x.  Columns with index <
// NW%NTN get 2 sharer waves (rows interleaved).  This cuts per-block L2 weight
// traffic ~4.7x (the binding resource per the R13 accounting).
// SWAP=true: D = mfma(W_frag, x_frag) -> lane col = x-dim, regs = weight-dim.
template<int NTN, int NTM, int KSTEPS, bool SWAP, typename Epi>
static __device__ __forceinline__ void gemm_phase_col(
    const unsigned short* __restrict__ opb,
    const uint4* __restrict__ wf, int set_base, int lane, int wave, Epi epi) {
  const int g8 = (lane >> 4) * 8;
  const int m16 = lane & 15;
  const int col    = wave % NTN;
  const int sharer = wave / NTN;
  const int nShare = (NW - 1 - col) / NTN + 1;
  uint4 wh[KSTEPS], wl[KSTEPS];
  #pragma unroll
  for (int ks = 0; ks < KSTEPS; ++ks) {
    size_t off = (size_t)(set_base + ks * NTN + col) * 64 + lane;
    wh[ks] = wf[off];
    wl[ks] = wf[(size_t)LO_V4 + off];
  }
  for (int r = sharer; r < NTM; r += nShare) {
    int mrow = r * 16 + m16; if (mrow > SEQ - 1) mrow = SEQ - 1;
    int abase = mrow * OPLD + g8;
    f32x4 a = {0.f, 0.f, 0.f, 0.f};
    #pragma unroll
    for (int ks = 0; ks < KSTEPS; ++ks) {
      half8v ah = *(const half8v*)&opb[abase + ks * 32];
      U16 h; h.u = wh[ks]; U16 l; l.u = wl[ks];
      if (SWAP) {
        a = MFMAH(h.h, ah, a);
        a = MFMAH(l.h, ah, a);
      } else {
        a = MFMAH(ah, h.h, a);
        a = MFMAH(ah, l.h, a);
      }
    }
    epi(r, col, a);
  }
}

__global__ __launch_bounds__(NT, 4) void fpfn_kernel(Params p) {
  __shared__ __align__(16) unsigned short R1[OPN];  // xT (fp16), [c][t]
  __shared__ __align__(16) unsigned short R2[OPN];  // x residual, [t][c] fp16
  __shared__ __align__(16) unsigned short R3[OPN];  // y1 [c][j] / y2 [t][j] fp16
  __shared__ float pe[640];
  __shared__ float sh[TLEN];                        // scaled history, later head partials
  __shared__ unsigned short datesu[TLEN * 4];

  const int tid  = threadIdx.x;
  const int b    = blockIdx.x;
  const int lane = tid & 63;
  const int wave = tid >> 6;

  // ---- zero operand buffers (pad regions must stay finite/zero) ----
  {
    uint4 z = {0, 0, 0, 0};
    uint4* z0 = (uint4*)R1;
    uint4* z1 = (uint4*)R2;
    uint4* z2 = (uint4*)R3;
    for (int i = tid; i < OPN / 8; i += NT) { z0[i] = z; z1[i] = z; z2[i] = z; }
  }

  float s = 0.f, hist_mean = 0.f;   // valid in wave 0 (used by tid 0 at the end)

  if (wave == 0) {
    // ---- robust_scale entirely in one wave (no block barriers) ----
    int t1 = lane + 64;
    bool v1 = (t1 < TLEN);
    float h0 = p.history[(size_t)b * TLEN + lane];
    float h1 = v1 ? p.history[(size_t)b * TLEN + t1] : 0.f;
    auto wred = [&](float v) -> float {
      #pragma unroll
      for (int o = 32; o > 0; o >>= 1) v += __shfl_xor(v, o, 64);
      return v;
    };
    float nz0 = (h0 != 0.f) ? 1.f : 0.f;
    float nz1 = (v1 && h1 != 0.f) ? 1.f : 0.f;
    float cnt  = wred(nz0 + nz1);
    float hsum = wred(h0 + h1);
    float safe = fmaxf(cnt, 1.f);
    float mean = hsum / safe;
    float var  = wred(nz0 * (h0 - mean) * (h0 - mean) + nz1 * (h1 - mean) * (h1 - mean)) / safe;
    float mean_z = (cnt > 0.f) ? mean : 0.f;
    float std_z  = (cnt > 0.f) ? sqrtf(var) : 0.f;
    float upper  = mean_z + 2.f * std_z;
    float c0v = fminf(fmaxf(h0, 0.f), upper);
    float c1v = fminf(fmaxf(h1, 0.f), upper);
    float m0 = (c0v != 0.f) ? 1.f : 0.f;
    float m1 = (v1 && c1v != 0.f) ? 1.f : 0.f;
    float cnt2 = wred(m0 + m1);
    float csum = wred(m0 * c0v + m1 * c1v);
    float safe2 = fmaxf(cnt2, 1.f);
    float mc = csum / safe2;
    float vc = wred(m0 * (c0v - mc) * (c0v - mc) + m1 * (c1v - mc) * (c1v - mc)) / safe2;
    float mc_z = (cnt2 > 0.f) ? mc : 0.f;
    float sc_z = (cnt2 > 0.f) ? sqrtf(vc) : 0.f;
    s = mc_z + sc_z + 1e-4f;
    hist_mean = hsum * (1.f / (float)TLEN);
    sh[lane] = fminf(fmaxf(h0 / s, 0.f), 3.f);
    if (v1) sh[t1] = fminf(fmaxf(h1 / s, 0.f), 3.f);
  } else {
    // ---- waves 1-7: positional tables + date offsets ----
    for (int idx = tid - 64; idx < 640; idx += (NT - 64)) {
      int periods, freqs, row, col;
      if (idx < 88)       { periods = 10; freqs = 4; row = idx >> 3;        col = idx & 7; }
      else if (idx < 192) { periods = 12; freqs = 4; row = (idx - 88) >> 3; col = (idx - 88) & 7; }
      else if (idx < 576) { periods = 31; freqs = 6; int r2 = idx - 192; row = r2 / 12; col = r2 - row * 12; }
      else                { periods = 7;  freqs = 4; row = (idx - 576) >> 3; col = (idx - 576) & 7; }
      int jf = (col < freqs) ? col : (col - freqs);
      float pip = (float)(3.14159265358979323846 / (double)periods);
      float ang = pip * (float)(1 << jf) * ((float)row - 1.0f);
      pe[idx] = (col < freqs) ? sinf(ang) : cosf(ang);
    }
    int t = tid - 64;
    if (t < TLEN) {
      int yr99 = p.ts[((size_t)b * TLEN + (TLEN - 1)) * 4 + 0];
      const int* tsb = p.ts + ((size_t)b * TLEN + t) * 4;
      int dy = yr99 - tsb[0]; dy = dy < 0 ? 0 : (dy > 10 ? 10 : dy);
      datesu[t * 4 + 0] = (unsigned short)(dy * 8);
      datesu[t * 4 + 1] = (unsigned short)(88  + tsb[1] * 8);
      datesu[t * 4 + 2] = (unsigned short)(192 + tsb[2] * 12);
      datesu[t * 4 + 3] = (unsigned short)(576 + tsb[3] * 8);
    }
  }
  __syncthreads();

  // ---- build x: fp16 into R2[t][j] and transposed into R1[j][t] ----
  for (int idx = tid; idx < DM * TLEN; idx += NT) {
    int j = idx / TLEN;
    int t = idx - j * TLEN;
    float sv = sh[t];
    float v;
    if (j < DE) {
      v = fmaxf(fmaf(sv, p.w_np[j], p.b_np[j]), 0.f);
    } else {
      int jj = j - DE;
      float e1 = fmaxf(fmaf(sv, p.w_wp[jj], p.b_wp[jj]), 0.f);
      float pv;
      if (jj < 8)       pv = pe[datesu[t * 4 + 0] + jj];
      else if (jj < 16) pv = pe[datesu[t * 4 + 1] + (jj - 8)];
      else if (jj < 28) pv = pe[datesu[t * 4 + 2] + (jj - 16)];
      else              pv = pe[datesu[t * 4 + 3] + (jj - 28)];
      v = e1 + pv;
    }
    unsigned short hv = f2h(v);
    R1[j * OPLD + t] = hv;
    R2[t * OPLD + j] = hv;
  }
  if (tid < DM) {  // target row t=100
    int tk = p.task[b];
    float te = p.task_emb[tk * DE + (tid < DE ? tid : tid - DE)];
    float v = te;
    if (tid >= DE) {
      int jj = tid - DE;
      const int* tt = p.target_ts + (size_t)b * 5;
      int yr99 = p.ts[((size_t)b * TLEN + (TLEN - 1)) * 4 + 0];
      int dy = yr99 - tt[0]; dy = dy < 0 ? 0 : (dy > 10 ? 10 : dy);
      float qv;
      if (jj < 8)       qv = pe[dy * 8 + jj];
      else if (jj < 16) qv = pe[88  + tt[1] * 8  + (jj - 8)];
      else if (jj < 28) qv = pe[192 + tt[2] * 12 + (jj - 16)];
      else              qv = pe[576 + tt[3] * 8  + (jj - 28)];
      v = te + qv;
    }
    unsigned short hv = f2h(v);
    R1[tid * OPLD + (SEQ - 1)] = hv;
    R2[(SEQ - 1) * OPLD + tid] = hv;
  }
  __syncthreads();

  const int m16 = lane & 15;
  const int rowb = (lane >> 4) * 4;

  #pragma unroll 1
  for (int rb = 0; rb < 2; ++rb) {
    const int base = rb * RB_SETS;
    const float* tb1 = p.tb1[rb]; const float* tb2 = p.tb2[rb];
    const float* cb1 = p.cb1[rb]; const float* cb2 = p.cb2[rb];

    // ---- A (SWAP): y1[c][j] = relu(tb1[j] + sum_t xT[c][t] tw1[t][j]);
    //      src R1(xT) -> dst R3(y1 as [c][j]); 5 j-cols x 5 c-rows ----
    gemm_phase_col<5, 5, 4, true>(R1, p.wf, base + 0, lane, wave,
      [&](int mt, int nt, f32x4 a) {
        int c  = mt * 16 + m16;
        int j0 = nt * 16 + rowb;
        if (c < DM && j0 < DM) {
          float4 b4 = *(const float4*)&tb1[j0];
          ushort4 hx;
          hx.x = f2h(fmaxf(a[0] + b4.x, 0.f));
          hx.y = f2h(fmaxf(a[1] + b4.y, 0.f));
          hx.z = f2h(fmaxf(a[2] + b4.z, 0.f));
          hx.w = f2h(fmaxf(a[3] + b4.w, 0.f));
          *(ushort4*)&R3[c * OPLD + j0] = hx;
        }
      });
    __syncthreads();

    // ---- B (no swap): x[t][c] += tb2[t] + sum_j y1[c][j] tw2[j][t];
    //      src R3(y1), x update in R2; 7 t-cols x 5 c-rows ----
    gemm_phase_col<7, 5, 3, false>(R3, p.wf, base + 20, lane, wave,
      [&](int mt, int nt, f32x4 a) {
        int t  = nt * 16 + m16;
        int c0 = mt * 16 + rowb;
        if (t < SEQ && c0 < DM) {        // c0 mult of 4; DM mult of 4 -> no straddle
          float bias = tb2[t];
          ushort4 xo = *(const ushort4*)&R2[t * OPLD + c0];
          ushort4 hx;
          hx.x = f2h(h2f(xo.x) + a[0] + bias);
          hx.y = f2h(h2f(xo.y) + a[1] + bias);
          hx.z = f2h(h2f(xo.z) + a[2] + bias);
          hx.w = f2h(h2f(xo.w) + a[3] + bias);
          *(ushort4*)&R2[t * OPLD + c0] = hx;
        }
      });
    __syncthreads();

    // ---- C (SWAP): y2[t][j] = relu(cb1[j] + sum_c x[t][c] cw1[c][j]);
    //      src R2(x) -> dst R3(y2 as [t][j]); 5 j-cols x 7 t-rows ----
    gemm_phase_col<5, 7, 3, true>(R2, p.wf, base + 41, lane, wave,
      [&](int mt, int nt, f32x4 a) {
        int t  = mt * 16 + m16;
        int j0 = nt * 16 + rowb;
        if (t < SEQ && j0 < DM) {
          float4 b4 = *(const float4*)&cb1[j0];
          ushort4 hx;
          hx.x = f2h(fmaxf(a[0] + b4.x, 0.f));
          hx.y = f2h(fmaxf(a[1] + b4.y, 0.f));
          hx.z = f2h(fmaxf(a[2] + b4.z, 0.f));
          hx.w = f2h(fmaxf(a[3] + b4.w, 0.f));
          *(ushort4*)&R3[t * OPLD + j0] = hx;
        }
      });
    __syncthreads();

    // ---- D (SWAP): x[t][c] += cb2[c] + sum_j y2[t][j] cw2[j][c];
    //      src R3(y2) -> R2 rmw (ushort4) + R1 xT (4 scalar); 5 c-cols x 7 t-rows ----
    gemm_phase_col<5, 7, 3, true>(R3, p.wf, base + 56, lane, wave,
      [&](int mt, int nt, f32x4 a) {
        int t  = mt * 16 + m16;
        int c0 = nt * 16 + rowb;
        if (t < SEQ && c0 < DM) {
          float4 cb4 = *(const float4*)&cb2[c0];
          ushort4 xo = *(const ushort4*)&R2[t * OPLD + c0];
          ushort4 hx;
          hx.x = f2h(h2f(xo.x) + a[0] + cb4.x);
          hx.y = f2h(h2f(xo.y) + a[1] + cb4.y);
          hx.z = f2h(h2f(xo.z) + a[2] + cb4.z);
          hx.w = f2h(h2f(xo.w) + a[3] + cb4.w);
          *(ushort4*)&R2[t * OPLD + c0] = hx;
          R1[(c0 + 0) * OPLD + t] = hx.x;   // xT for next resblock's A
          R1[(c0 + 1) * OPLD + t] = hx.y;
          R1[(c0 + 2) * OPLD + t] = hx.z;
          R1[(c0 + 3) * OPLD + t] = hx.w;
        }
      });
    __syncthreads();
  }

  // ---- head (fp32 math on fp16 x) ----
  if (tid < DM) {
    float a = 0.f;
    for (int t = 0; t < SEQ; ++t) a = fmaf(h2f(R2[t * OPLD + tid]), p.wp_time[t], a);
    sh[tid] = (a + p.bp_time[0]) * p.w_head[tid];
  }
  __syncthreads();
  if (tid == 0) {
    float yv = 0.f;
    #pragma unroll 8
    for (int i = 0; i < DM; ++i) yv += sh[i];
    yv = fmaxf(yv + p.b_head[0], 0.f);
    p.out[b]      = yv * s + hist_mean;
    p.out[NB + b] = s;
  }
}

extern "C" void kernel_launch(void* const* d_in, const int* in_sizes, int n_in,
                              void* d_out, int out_size, void* d_ws, size_t ws_size,
                              hipStream_t stream) {
  (void)in_sizes; (void)n_in; (void)out_size; (void)ws_size;

  SetupParams sp;
  sp.tw1[0] = (const float*)d_in[9];  sp.tw2[0] = (const float*)d_in[11];
  sp.cw1[0] = (const float*)d_in[13]; sp.cw2[0] = (const float*)d_in[15];
  sp.tw1[1] = (const float*)d_in[17]; sp.tw2[1] = (const float*)d_in[19];
  sp.cw1[1] = (const float*)d_in[21]; sp.cw2[1] = (const float*)d_in[23];
  sp.ws = (unsigned*)d_ws;
  hipLaunchKernelGGL(setup_kernel, dim3(TOTAL_SETS), dim3(256), 0, stream, sp);

  Params p;
  p.history   = (const float*)d_in[0];
  p.ts        = (const int*)  d_in[1];
  p.target_ts = (const int*)  d_in[2];
  p.task      = (const int*)  d_in[3];
  p.w_np = (const float*)d_in[4];  p.b_np = (const float*)d_in[5];
  p.w_wp = (const float*)d_in[6];  p.b_wp = (const float*)d_in[7];
  p.task_emb = (const float*)d_in[8];
  p.tb1[0] = (const float*)d_in[10]; p.tb2[0] = (const float*)d_in[12];
  p.cb1[0] = (const float*)d_in[14]; p.cb2[0] = (const float*)d_in[16];
  p.tb1[1] = (const float*)d_in[18]; p.tb2[1] = (const float*)d_in[20];
  p.cb1[1] = (const float*)d_in[22]; p.cb2[1] = (const float*)d_in[24];
  p.wp_time = (const float*)d_in[25]; p.bp_time = (const float*)d_in[26];
  p.w_head  = (const float*)d_in[27]; p.b_head  = (const float*)d_in[28];
  p.wf  = (const uint4*)d_ws;
  p.out = (float*)d_out;
  hipLaunchKernelGGL(fpfn_kernel, dim3(NB), dim3(NT), 0, stream, p);
}

// Round 15
// 337.342 us; speedup vs baseline: 2.1807x; 1.1807x over previous
//
#include <hip/hip_runtime.h>
#include <math.h>

#define NB   8192
#define TLEN 100
#define SEQ  101
#define DE   36
#define DM   72
#define NT   512    // threads per block (8 waves)
#define NW   8      // waves per block
#define OPLD 104    // operand row stride (fp16 elems); mult of 8 -> 16B-aligned b128
#define OPN  10528  // 101*104 + tail slack for clamped k-tail reads (x0 weights)

// frag sets per resblock: A:4k*5n=20, B:3*7=21, C:3*5=15, D:3*5=15 -> 71
#define RB_SETS    71
#define TOTAL_SETS 142

typedef _Float16 half8v __attribute__((ext_vector_type(8)));
typedef __attribute__((ext_vector_type(4))) float f32x4;
union U16 { uint4 u; half8v h; };

#define MFMAH(a, b, c) __builtin_amdgcn_mfma_f32_16x16x32_f16((a), (b), (c), 0, 0, 0)

static __device__ __forceinline__ unsigned short f2h(float f) {
  union { _Float16 h; unsigned short u; } c;
  c.h = (_Float16)f;
  return c.u;
}
static __device__ __forceinline__ float h2f(unsigned short u) {
  union { _Float16 h; unsigned short u; } c;
  c.u = u;
  return (float)c.h;
}

struct SetupParams {
  const float* tw1[2]; const float* tw2[2]; const float* cw1[2]; const float* cw2[2];
  unsigned* ws;
};

// Pack weights into MFMA fragment order as fp16 (round-to-nearest),
// zero-padded for k >= K and n >= N.  Slot bijection: k = kstep*32 + (lane>>4)*8 + e,
// n = ntile*16 + (lane&15); dword r holds elements e=2r (lo16) and e=2r+1 (hi16).
// A- and B-operand fragments share this bijection (operand-swap safe).
// Single-term fp16 weights: error audit (R5 absmax=0.0 w/ fp32 residual vs
// R6+ 0.0039 w/ fp16 residual) shows output error is residual-storage-
// dominated; W quantization adds ~1e-4, invisible at the 0.0039 level.
__global__ void setup_kernel(SetupParams sp) {
  int s = blockIdx.x;           // set id 0..141
  int tid = threadIdx.x;        // 256
  int l = tid >> 2, r = tid & 3;
  int rb = s / RB_SETS, s2 = s % RB_SETS;
  const float* W; int K, N, ks, nt;
  if (s2 < 20)      { ks = s2 / 5;        nt = s2 % 5;        W = sp.tw1[rb]; K = SEQ; N = DM; }
  else if (s2 < 41) { int t = s2 - 20; ks = t / 7; nt = t % 7; W = sp.tw2[rb]; K = DM;  N = SEQ; }
  else if (s2 < 56) { int t = s2 - 41; ks = t / 5; nt = t % 5; W = sp.cw1[rb]; K = DM;  N = DM; }
  else              { int t = s2 - 56; ks = t / 5; nt = t % 5; W = sp.cw2[rb]; K = DM;  N = DM; }
  int g = l >> 4;
  int n = nt * 16 + (l & 15);
  int k0 = ks * 32 + g * 8 + 2 * r;
  int k1 = k0 + 1;
  float f0 = (k0 < K && n < N) ? W[k0 * N + n] : 0.f;
  float f1 = (k1 < K && n < N) ? W[k1 * N + n] : 0.f;
  union { _Float16 h; unsigned short u; } h0, h1;
  h0.h = (_Float16)f0; h1.h = (_Float16)f1;
  unsigned idx = (unsigned)s * 256u + (unsigned)l * 4u + (unsigned)r;
  sp.ws[idx] = (unsigned)h0.u | ((unsigned)h1.u << 16);
}

struct Params {
  const float *history; const int *ts; const int *target_ts; const int *task;
  const float *w_np; const float *b_np; const float *w_wp; const float *b_wp;
  const float *task_emb;
  const float *tb1[2]; const float *tb2[2]; const float *cb1[2]; const float *cb2[2];
  const float *wp_time; const float *bp_time; const float *w_head; const float *b_head;
  const uint4 *wf; float *out;
};

// Column-ownership GEMM phase: each wave owns ONE weight column (nt) and
// iterates the row tiles of that column, so the column's weight fragments are
// loaded from L2 exactly once per wave and reused 3-7x (R14: the L2-traffic
// cut was worth 1.47x).  Columns with index < NW%NTN get 2 sharer waves.
// SWAP=true: D = mfma(W_frag, x_frag) -> lane col = x-dim, regs = weight-dim.
template<int NTN, int NTM, int KSTEPS, bool SWAP, typename Epi>
static __device__ __forceinline__ void gemm_phase_col(
    const unsigned short* __restrict__ opb,
    const uint4* __restrict__ wf, int set_base, int lane, int wave, Epi epi) {
  const int g8 = (lane >> 4) * 8;
  const int m16 = lane & 15;
  const int col    = wave % NTN;
  const int sharer = wave / NTN;
  const int nShare = (NW - 1 - col) / NTN + 1;
  uint4 wh[KSTEPS];
  #pragma unroll
  for (int ks = 0; ks < KSTEPS; ++ks) {
    size_t off = (size_t)(set_base + ks * NTN + col) * 64 + lane;
    wh[ks] = wf[off];
  }
  for (int r = sharer; r < NTM; r += nShare) {
    int mrow = r * 16 + m16; if (mrow > SEQ - 1) mrow = SEQ - 1;
    int abase = mrow * OPLD + g8;
    f32x4 a = {0.f, 0.f, 0.f, 0.f};
    #pragma unroll
    for (int ks = 0; ks < KSTEPS; ++ks) {
      half8v ah = *(const half8v*)&opb[abase + ks * 32];
      U16 h; h.u = wh[ks];
      if (SWAP) a = MFMAH(h.h, ah, a);
      else      a = MFMAH(ah, h.h, a);
    }
    epi(r, col, a);
  }
}

__global__ __launch_bounds__(NT, 4) void fpfn_kernel(Params p) {
  __shared__ __align__(16) unsigned short R1[OPN];  // xT (fp16), [c][t]
  __shared__ __align__(16) unsigned short R2[OPN];  // x residual, [t][c] fp16
  __shared__ __align__(16) unsigned short R3[OPN];  // y1 [c][j] / y2 [t][j] fp16
  __shared__ float pe[640];
  __shared__ float sh[TLEN];                        // scaled history, later head partials
  __shared__ unsigned short datesu[TLEN * 4];

  const int tid  = threadIdx.x;
  const int b    = blockIdx.x;
  const int lane = tid & 63;
  const int wave = tid >> 6;

  // ---- zero operand buffers (pad regions must stay finite/zero) ----
  {
    uint4 z = {0, 0, 0, 0};
    uint4* z0 = (uint4*)R1;
    uint4* z1 = (uint4*)R2;
    uint4* z2 = (uint4*)R3;
    for (int i = tid; i < OPN / 8; i += NT) { z0[i] = z; z1[i] = z; z2[i] = z; }
  }

  float s = 0.f, hist_mean = 0.f;   // valid in wave 0 (used by tid 0 at the end)

  if (wave == 0) {
    // ---- robust_scale entirely in one wave (no block barriers) ----
    int t1 = lane + 64;
    bool v1 = (t1 < TLEN);
    float h0 = p.history[(size_t)b * TLEN + lane];
    float h1 = v1 ? p.history[(size_t)b * TLEN + t1] : 0.f;
    auto wred = [&](float v) -> float {
      #pragma unroll
      for (int o = 32; o > 0; o >>= 1) v += __shfl_xor(v, o, 64);
      return v;
    };
    float nz0 = (h0 != 0.f) ? 1.f : 0.f;
    float nz1 = (v1 && h1 != 0.f) ? 1.f : 0.f;
    float cnt  = wred(nz0 + nz1);
    float hsum = wred(h0 + h1);
    float safe = fmaxf(cnt, 1.f);
    float mean = hsum / safe;
    float var  = wred(nz0 * (h0 - mean) * (h0 - mean) + nz1 * (h1 - mean) * (h1 - mean)) / safe;
    float mean_z = (cnt > 0.f) ? mean : 0.f;
    float std_z  = (cnt > 0.f) ? sqrtf(var) : 0.f;
    float upper  = mean_z + 2.f * std_z;
    float c0v = fminf(fmaxf(h0, 0.f), upper);
    float c1v = fminf(fmaxf(h1, 0.f), upper);
    float m0 = (c0v != 0.f) ? 1.f : 0.f;
    float m1 = (v1 && c1v != 0.f) ? 1.f : 0.f;
    float cnt2 = wred(m0 + m1);
    float csum = wred(m0 * c0v + m1 * c1v);
    float safe2 = fmaxf(cnt2, 1.f);
    float mc = csum / safe2;
    float vc = wred(m0 * (c0v - mc) * (c0v - mc) + m1 * (c1v - mc) * (c1v - mc)) / safe2;
    float mc_z = (cnt2 > 0.f) ? mc : 0.f;
    float sc_z = (cnt2 > 0.f) ? sqrtf(vc) : 0.f;
    s = mc_z + sc_z + 1e-4f;
    hist_mean = hsum * (1.f / (float)TLEN);
    sh[lane] = fminf(fmaxf(h0 / s, 0.f), 3.f);
    if (v1) sh[t1] = fminf(fmaxf(h1 / s, 0.f), 3.f);
  } else {
    // ---- waves 1-7: positional tables + date offsets ----
    for (int idx = tid - 64; idx < 640; idx += (NT - 64)) {
      int periods, freqs, row, col;
      if (idx < 88)       { periods = 10; freqs = 4; row = idx >> 3;        col = idx & 7; }
      else if (idx < 192) { periods = 12; freqs = 4; row = (idx - 88) >> 3; col = (idx - 88) & 7; }
      else if (idx < 576) { periods = 31; freqs = 6; int r2 = idx - 192; row = r2 / 12; col = r2 - row * 12; }
      else                { periods = 7;  freqs = 4; row = (idx - 576) >> 3; col = (idx - 576) & 7; }
      int jf = (col < freqs) ? col : (col - freqs);
      float pip = (float)(3.14159265358979323846 / (double)periods);
      float ang = pip * (float)(1 << jf) * ((float)row - 1.0f);
      pe[idx] = (col < freqs) ? sinf(ang) : cosf(ang);
    }
    int t = tid - 64;
    if (t < TLEN) {
      int yr99 = p.ts[((size_t)b * TLEN + (TLEN - 1)) * 4 + 0];
      const int* tsb = p.ts + ((size_t)b * TLEN + t) * 4;
      int dy = yr99 - tsb[0]; dy = dy < 0 ? 0 : (dy > 10 ? 10 : dy);
      datesu[t * 4 + 0] = (unsigned short)(dy * 8);
      datesu[t * 4 + 1] = (unsigned short)(88  + tsb[1] * 8);
      datesu[t * 4 + 2] = (unsigned short)(192 + tsb[2] * 12);
      datesu[t * 4 + 3] = (unsigned short)(576 + tsb[3] * 8);
    }
  }
  __syncthreads();

  // ---- build x: fp16 into R2[t][j] and transposed into R1[j][t] ----
  for (int idx = tid; idx < DM * TLEN; idx += NT) {
    int j = idx / TLEN;
    int t = idx - j * TLEN;
    float sv = sh[t];
    float v;
    if (j < DE) {
      v = fmaxf(fmaf(sv, p.w_np[j], p.b_np[j]), 0.f);
    } else {
      int jj = j - DE;
      float e1 = fmaxf(fmaf(sv, p.w_wp[jj], p.b_wp[jj]), 0.f);
      float pv;
      if (jj < 8)       pv = pe[datesu[t * 4 + 0] + jj];
      else if (jj < 16) pv = pe[datesu[t * 4 + 1] + (jj - 8)];
      else if (jj < 28) pv = pe[datesu[t * 4 + 2] + (jj - 16)];
      else              pv = pe[datesu[t * 4 + 3] + (jj - 28)];
      v = e1 + pv;
    }
    unsigned short hv = f2h(v);
    R1[j * OPLD + t] = hv;
    R2[t * OPLD + j] = hv;
  }
  if (tid < DM) {  // target row t=100
    int tk = p.task[b];
    float te = p.task_emb[tk * DE + (tid < DE ? tid : tid - DE)];
    float v = te;
    if (tid >= DE) {
      int jj = tid - DE;
      const int* tt = p.target_ts + (size_t)b * 5;
      int yr99 = p.ts[((size_t)b * TLEN + (TLEN - 1)) * 4 + 0];
      int dy = yr99 - tt[0]; dy = dy < 0 ? 0 : (dy > 10 ? 10 : dy);
      float qv;
      if (jj < 8)       qv = pe[dy * 8 + jj];
      else if (jj < 16) qv = pe[88  + tt[1] * 8  + (jj - 8)];
      else if (jj < 28) qv = pe[192 + tt[2] * 12 + (jj - 16)];
      else              qv = pe[576 + tt[3] * 8  + (jj - 28)];
      v = te + qv;
    }
    unsigned short hv = f2h(v);
    R1[tid * OPLD + (SEQ - 1)] = hv;
    R2[(SEQ - 1) * OPLD + tid] = hv;
  }
  __syncthreads();

  const int m16 = lane & 15;
  const int rowb = (lane >> 4) * 4;

  #pragma unroll 1
  for (int rb = 0; rb < 2; ++rb) {
    const int base = rb * RB_SETS;
    const float* tb1 = p.tb1[rb]; const float* tb2 = p.tb2[rb];
    const float* cb1 = p.cb1[rb]; const float* cb2 = p.cb2[rb];

    // ---- A (SWAP): y1[c][j] = relu(tb1[j] + sum_t xT[c][t] tw1[t][j]);
    //      src R1(xT) -> dst R3(y1 as [c][j]); 5 j-cols x 5 c-rows ----
    gemm_phase_col<5, 5, 4, true>(R1, p.wf, base + 0, lane, wave,
      [&](int mt, int nt, f32x4 a) {
        int c  = mt * 16 + m16;
        int j0 = nt * 16 + rowb;
        if (c < DM && j0 < DM) {
          float4 b4 = *(const float4*)&tb1[j0];
          ushort4 hx;
          hx.x = f2h(fmaxf(a[0] + b4.x, 0.f));
          hx.y = f2h(fmaxf(a[1] + b4.y, 0.f));
          hx.z = f2h(fmaxf(a[2] + b4.z, 0.f));
          hx.w = f2h(fmaxf(a[3] + b4.w, 0.f));
          *(ushort4*)&R3[c * OPLD + j0] = hx;
        }
      });
    __syncthreads();

    // ---- B (no swap): x[t][c] += tb2[t] + sum_j y1[c][j] tw2[j][t];
    //      src R3(y1), x update in R2; 7 t-cols x 5 c-rows ----
    gemm_phase_col<7, 5, 3, false>(R3, p.wf, base + 20, lane, wave,
      [&](int mt, int nt, f32x4 a) {
        int t  = nt * 16 + m16;
        int c0 = mt * 16 + rowb;
        if (t < SEQ && c0 < DM) {        // c0 mult of 4; DM mult of 4 -> no straddle
          float bias = tb2[t];
          ushort4 xo = *(const ushort4*)&R2[t * OPLD + c0];
          ushort4 hx;
          hx.x = f2h(h2f(xo.x) + a[0] + bias);
          hx.y = f2h(h2f(xo.y) + a[1] + bias);
          hx.z = f2h(h2f(xo.z) + a[2] + bias);
          hx.w = f2h(h2f(xo.w) + a[3] + bias);
          *(ushort4*)&R2[t * OPLD + c0] = hx;
        }
      });
    __syncthreads();

    // ---- C (SWAP): y2[t][j] = relu(cb1[j] + sum_c x[t][c] cw1[c][j]);
    //      src R2(x) -> dst R3(y2 as [t][j]); 5 j-cols x 7 t-rows ----
    gemm_phase_col<5, 7, 3, true>(R2, p.wf, base + 41, lane, wave,
      [&](int mt, int nt, f32x4 a) {
        int t  = mt * 16 + m16;
        int j0 = nt * 16 + rowb;
        if (t < SEQ && j0 < DM) {
          float4 b4 = *(const float4*)&cb1[j0];
          ushort4 hx;
          hx.x = f2h(fmaxf(a[0] + b4.x, 0.f));
          hx.y = f2h(fmaxf(a[1] + b4.y, 0.f));
          hx.z = f2h(fmaxf(a[2] + b4.z, 0.f));
          hx.w = f2h(fmaxf(a[3] + b4.w, 0.f));
          *(ushort4*)&R3[t * OPLD + j0] = hx;
        }
      });
    __syncthreads();

    // ---- D (SWAP): x[t][c] += cb2[c] + sum_j y2[t][j] cw2[j][c];
    //      src R3(y2) -> R2 rmw (ushort4) + R1 xT (4 scalar); 5 c-cols x 7 t-rows ----
    gemm_phase_col<5, 7, 3, true>(R3, p.wf, base + 56, lane, wave,
      [&](int mt, int nt, f32x4 a) {
        int t  = mt * 16 + m16;
        int c0 = nt * 16 + rowb;
        if (t < SEQ && c0 < DM) {
          float4 cb4 = *(const float4*)&cb2[c0];
          ushort4 xo = *(const ushort4*)&R2[t * OPLD + c0];
          ushort4 hx;
          hx.x = f2h(h2f(xo.x) + a[0] + cb4.x);
          hx.y = f2h(h2f(xo.y) + a[1] + cb4.y);
          hx.z = f2h(h2f(xo.z) + a[2] + cb4.z);
          hx.w = f2h(h2f(xo.w) + a[3] + cb4.w);
          *(ushort4*)&R2[t * OPLD + c0] = hx;
          R1[(c0 + 0) * OPLD + t] = hx.x;   // xT for next resblock's A
          R1[(c0 + 1) * OPLD + t] = hx.y;
          R1[(c0 + 2) * OPLD + t] = hx.z;
          R1[(c0 + 3) * OPLD + t] = hx.w;
        }
      });
    __syncthreads();
  }

  // ---- head (fp32 math on fp16 x) ----
  if (tid < DM) {
    float a = 0.f;
    for (int t = 0; t < SEQ; ++t) a = fmaf(h2f(R2[t * OPLD + tid]), p.wp_time[t], a);
    sh[tid] = (a + p.bp_time[0]) * p.w_head[tid];
  }
  __syncthreads();
  if (tid == 0) {
    float yv = 0.f;
    #pragma unroll 8
    for (int i = 0; i < DM; ++i) yv += sh[i];
    yv = fmaxf(yv + p.b_head[0], 0.f);
    p.out[b]      = yv * s + hist_mean;
    p.out[NB + b] = s;
  }
}

extern "C" void kernel_launch(void* const* d_in, const int* in_sizes, int n_in,
                              void* d_out, int out_size, void* d_ws, size_t ws_size,
                              hipStream_t stream) {
  (void)in_sizes; (void)n_in; (void)out_size; (void)ws_size;

  SetupParams sp;
  sp.tw1[0] = (const float*)d_in[9];  sp.tw2[0] = (const float*)d_in[11];
  sp.cw1[0] = (const float*)d_in[13]; sp.cw2[0] = (const float*)d_in[15];
  sp.tw1[1] = (const float*)d_in[17]; sp.tw2[1] = (const float*)d_in[19];
  sp.cw1[1] = (const float*)d_in[21]; sp.cw2[1] = (const float*)d_in[23];
  sp.ws = (unsigned*)d_ws;
  hipLaunchKernelGGL(setup_kernel, dim3(TOTAL_SETS), dim3(256), 0, stream, sp);

  Params p;
  p.history   = (const float*)d_in[0];
  p.ts        = (const int*)  d_in[1];
  p.target_ts = (const int*)  d_in[2];
  p.task      = (const int*)  d_in[3];
  p.w_np = (const float*)d_in[4];  p.b_np = (const float*)d_in[5];
  p.w_wp = (const float*)d_in[6];  p.b_wp = (const float*)d_in[7];
  p.task_emb = (const float*)d_in[8];
  p.tb1[0] = (const float*)d_in[10]; p.tb2[0] = (const float*)d_in[12];
  p.cb1[0] = (const float*)d_in[14]; p.cb2[0] = (const float*)d_in[16];
  p.tb1[1] = (const float*)d_in[18]; p.tb2[1] = (const float*)d_in[20];
  p.cb1[1] = (const float*)d_in[22]; p.cb2[1] = (const float*)d_in[24];
  p.wp_time = (const float*)d_in[25]; p.bp_time = (const float*)d_in[26];
  p.w_head  = (const float*)d_in[27]; p.b_head  = (const float*)d_in[28];
  p.wf  = (const uint4*)d_ws;
  p.out = (float*)d_out;
  hipLaunchKernelGGL(fpfn_kernel, dim3(NB), dim3(NT), 0, stream, p);
}